// Round 5
// baseline (17620.222 us; speedup 1.0000x reference)
//
#include <hip/hip_runtime.h>
#include <math.h>

#define BB 64
#define SS 512
#define DD 207
#define HH 256

// ---- persistent-sharded design, v4b: fence-free sc1 exchange ----
// 64 WGs x 256 threads. WG w owns hidden units [4w,4w+4) (12 gate rows) and
// readout rows [d0,d1). Weights LDS-resident. Cross-WG data moves ONLY via
// agent-scope relaxed atomics (sc1 -> coherence point). No fences =>
// no buffer_wbl2/buffer_inv (round-3's 13us/step killer).
// actg[928][64] fp32 in ws:
//   rows 0..413   : xin (x-part 0..206, mask-part 207..413)
//   rows 414..415 : zero pad (weight cols also zeroed)
//   rows 416..671 : h parity 0
//   rows 672..927 : h parity 1
// flags: 64 x 32 uints (128B spacing); monotone generations.
#define AROWS 928
#define HBASE 416
#define ACT_FLOATS (AROWS * 64)
#define FLAG_FLOATS (64 * 32)
#define STAGE_FLOATS (SS * DD * 64)
#define WS_SMALL ((size_t)(ACT_FLOATS + FLAG_FLOATS) * sizeof(float))
#define WS_FULL  ((size_t)(ACT_FLOATS + FLAG_FLOATS + STAGE_FLOATS) * sizeof(float))
#define NWG 64
#define LDW 676   // wgl row stride: %32 = 4 -> u-staggered banks
#define ROW 260   // wrol row stride: %32 = 4 -> dl-staggered banks
#define AG __HIP_MEMORY_SCOPE_AGENT

union U2 { unsigned long long u; float2 f; };

__device__ __forceinline__ unsigned long long ald8(const float* p) {
    return __hip_atomic_load((const unsigned long long*)p, __ATOMIC_RELAXED, AG);
}
__device__ __forceinline__ void ast4(float* p, float v) {
    union { float f; unsigned u; } c; c.f = v;
    __hip_atomic_store((unsigned*)p, c.u, __ATOMIC_RELAXED, AG);
}

// load 4 consecutive activation rows (this lane's batch quad) as 2 x 8B each
__device__ __forceinline__ void load_quad(U2 q[4][2], const float* act, int row0, int bp) {
    #pragma unroll
    for (int kk = 0; kk < 4; ++kk) {
        const float* pr = act + (row0 + kk) * 64 + bp * 4;
        q[kk][0].u = ald8(pr);
        q[kk][1].u = ald8(pr + 2);
    }
}

// 12-row (3 gates x unit u) FMA for one 4-row quad of activations
__device__ __forceinline__ void fma_quad(float c0[4], float c1[4], float c2[4],
    const U2 q[4][2], const float* __restrict__ wgl, int u, int col)
{
    float4 w0 = *(const float4*)&wgl[(0 + u) * LDW + col];
    float4 w1 = *(const float4*)&wgl[(4 + u) * LDW + col];
    float4 w2 = *(const float4*)&wgl[(8 + u) * LDW + col];
    #pragma unroll
    for (int kk = 0; kk < 4; ++kk) {
        float aa[4] = { q[kk][0].f.x, q[kk][0].f.y, q[kk][1].f.x, q[kk][1].f.y };
        float wk0 = (&w0.x)[kk], wk1 = (&w1.x)[kk], wk2 = (&w2.x)[kk];
        #pragma unroll
        for (int bb = 0; bb < 4; ++bb) {
            c0[bb] += aa[bb] * wk0;
            c1[bb] += aa[bb] * wk1;
            c2[bb] += aa[bb] * wk2;
        }
    }
}

// depth-4-pipelined 12-row GEMV partial over k-range [wc0, wc0+len), acts from
// global rows [ar0, ar0+len) via sc1. lane = (u = lane>>4, bp = lane&15).
__device__ __forceinline__ void gemv12_pipe(
    const float* __restrict__ act, const float* __restrict__ wgl,
    float* __restrict__ red, int u, int bp, int wc0, int ar0, int len, int slot)
{
    float c0[4] = {0,0,0,0}, c1[4] = {0,0,0,0}, c2[4] = {0,0,0,0};
    U2 q0[4][2], q1[4][2], q2[4][2], q3[4][2];
    const int nq = len >> 2;   // len multiple of 4, nq >= 4
    load_quad(q0, act, ar0 + 0,  bp);
    load_quad(q1, act, ar0 + 4,  bp);
    load_quad(q2, act, ar0 + 8,  bp);
    load_quad(q3, act, ar0 + 12, bp);
    int kq = 0;
    for (; kq + 4 <= nq; kq += 4) {
        fma_quad(c0, c1, c2, q0, wgl, u, wc0 + (kq + 0) * 4);
        if (kq + 4 < nq) load_quad(q0, act, ar0 + (kq + 4) * 4, bp);
        fma_quad(c0, c1, c2, q1, wgl, u, wc0 + (kq + 1) * 4);
        if (kq + 5 < nq) load_quad(q1, act, ar0 + (kq + 5) * 4, bp);
        fma_quad(c0, c1, c2, q2, wgl, u, wc0 + (kq + 2) * 4);
        if (kq + 6 < nq) load_quad(q2, act, ar0 + (kq + 6) * 4, bp);
        fma_quad(c0, c1, c2, q3, wgl, u, wc0 + (kq + 3) * 4);
        if (kq + 7 < nq) load_quad(q3, act, ar0 + (kq + 7) * 4, bp);
    }
    if (kq + 0 < nq) fma_quad(c0, c1, c2, q0, wgl, u, wc0 + (kq + 0) * 4);
    if (kq + 1 < nq) fma_quad(c0, c1, c2, q1, wgl, u, wc0 + (kq + 1) * 4);
    if (kq + 2 < nq) fma_quad(c0, c1, c2, q2, wgl, u, wc0 + (kq + 2) * 4);
    if (kq + 3 < nq) fma_quad(c0, c1, c2, q3, wgl, u, wc0 + (kq + 3) * 4);
    float4* R4 = (float4*)red;
    R4[(slot * 12 + 0 + u) * 16 + bp] = *(float4*)c0;
    R4[(slot * 12 + 4 + u) * 16 + bp] = *(float4*)c1;
    R4[(slot * 12 + 8 + u) * 16 + bp] = *(float4*)c2;
}

// readout FMA: one row u, one 4-row quad
__device__ __forceinline__ void fma_ro(float c[4], const U2 q[4][2],
    const float* __restrict__ wrol, int u, int col)
{
    float4 w = *(const float4*)&wrol[u * ROW + col];
    #pragma unroll
    for (int kk = 0; kk < 4; ++kk) {
        float aa[4] = { q[kk][0].f.x, q[kk][0].f.y, q[kk][1].f.x, q[kk][1].f.y };
        float wk = (&w.x)[kk];
        #pragma unroll
        for (int bb = 0; bb < 4; ++bb) c[bb] += aa[bb] * wk;
    }
}

// depth-4-pipelined readout partial: row u (0..3), wave k-slice jb = wv*64.
__device__ __forceinline__ void gemv_ro_pipe(
    const float* __restrict__ act, const float* __restrict__ wrol,
    float* __restrict__ redB, int u, int bp, int wv, int hrow0)
{
    const int jb = wv * 64;
    float c[4] = {0,0,0,0};
    U2 q0[4][2], q1[4][2], q2[4][2], q3[4][2];
    load_quad(q0, act, hrow0 + jb + 0,  bp);
    load_quad(q1, act, hrow0 + jb + 4,  bp);
    load_quad(q2, act, hrow0 + jb + 8,  bp);
    load_quad(q3, act, hrow0 + jb + 12, bp);
    #pragma unroll
    for (int kq = 0; kq < 16; kq += 4) {
        fma_ro(c, q0, wrol, u, jb + (kq + 0) * 4);
        if (kq + 4 < 16) load_quad(q0, act, hrow0 + jb + (kq + 4) * 4, bp);
        fma_ro(c, q1, wrol, u, jb + (kq + 1) * 4);
        if (kq + 5 < 16) load_quad(q1, act, hrow0 + jb + (kq + 5) * 4, bp);
        fma_ro(c, q2, wrol, u, jb + (kq + 2) * 4);
        if (kq + 6 < 16) load_quad(q2, act, hrow0 + jb + (kq + 6) * 4, bp);
        fma_ro(c, q3, wrol, u, jb + (kq + 3) * 4);
        if (kq + 7 < 16) load_quad(q3, act, hrow0 + jb + (kq + 7) * 4, bp);
    }
    *(float4*)&redB[(wv * 4 + u) * 64 + bp * 4] = *(float4*)c;
}

__global__ __launch_bounds__(256) void rnn_init(float* __restrict__ ws) {
    int i = blockIdx.x * blockDim.x + threadIdx.x;
    const int nz = (672 - 414) * 64;  // pad rows + h parity 0
    for (int idx = i; idx < nz; idx += gridDim.x * blockDim.x)
        ws[414 * 64 + idx] = 0.f;
    for (int idx = i; idx < FLAG_FLOATS; idx += gridDim.x * blockDim.x)
        ((unsigned*)(ws + ACT_FLOATS))[idx] = 0u;
}

template<bool STAGE>
__global__ __launch_bounds__(256) void rnn_persist(
    const float* __restrict__ x, const float* __restrict__ mask,
    const float* __restrict__ W_ih, const float* __restrict__ W_hh,
    const float* __restrict__ b_ih, const float* __restrict__ b_hh,
    const float* __restrict__ W_ro, const float* __restrict__ b_ro,
    float* __restrict__ ws, float* __restrict__ out)
{
    const int wg = blockIdx.x;
    const int tid = threadIdx.x;
    const int lane = tid & 63;
    const int wv = tid >> 6;

    float* actg = ws;
    unsigned* flags = (unsigned*)(ws + ACT_FLOATS);
    float* stage = ws + ACT_FLOATS + FLAG_FLOATS;

    __shared__ float wgl[12 * LDW];     // 12 gate rows x 676 (cols 414/415 = 0)
    __shared__ float wrol[4 * ROW];     // up to 4 readout rows, stride 260
    __shared__ float red[8 * 12 * 64];  // gate partials: slots 0-3 xin, 4-7 gh
    __shared__ float redB[16 * 64];     // readout partials (4 waves x 4 rows)
    __shared__ float hloc[4 * 64];      // own hidden units
    __shared__ float bihl[12], bhhl[12], brol[4];

    const int d0 = (207 * wg) / NWG;
    const int d1 = (207 * (wg + 1)) / NWG;
    const int dc = d1 - d0;

    for (int i = tid; i < 12 * LDW; i += 256) {
        int r = i / LDW, c = i - r * LDW;
        int rg = (r >> 2) * 256 + wg * 4 + (r & 3);
        float v = 0.f;
        if (c < 414) v = W_ih[rg * 414 + c];
        else if (c >= 416 && c < 672) v = W_hh[rg * 256 + (c - 416)];
        wgl[i] = v;
    }
    for (int i = tid; i < 4 * 256; i += 256) {
        int dl_ = i >> 8, j = i & 255;
        wrol[dl_ * ROW + j] = (dl_ < dc) ? W_ro[(d0 + dl_) * 256 + j] : 0.f;
    }
    if (tid < 12) {
        int rg = (tid >> 2) * 256 + wg * 4 + (tid & 3);
        bihl[tid] = b_ih[rg];
        bhhl[tid] = b_hh[rg];
    }
    if (tid < 4) brol[tid] = (tid < dc) ? b_ro[d0 + tid] : 0.f;
    hloc[tid] = 0.f;
    __syncthreads();

    const int u  = lane >> 4;   // unit (gates) / readout row (readout phase)
    const int bp = lane & 15;   // batch quad

    const bool have = (tid < dc * 64);
    const int dl = tid >> 6, b = tid & 63;
    const size_t gbase = (size_t)b * (SS * DD) + (d0 + dl);
    float xv_pf = 0.f, mv_pf = 0.f;
    if (have) { xv_pf = x[gbase]; mv_pf = mask[gbase]; }

    unsigned gen = 0;

    for (int t = 0; t < SS; ++t) {
        const int par = t & 1;
        const int hrow0 = HBASE + par * 256;   // actg row of h_t[0]

        // ---- Phase B: readout partials ----
        gemv_ro_pipe(actg, wrol, redB, u, bp, wv, hrow0);
        __syncthreads();
        if (have) {
            float xh = redB[(0 * 4 + dl) * 64 + b] + redB[(1 * 4 + dl) * 64 + b]
                     + redB[(2 * 4 + dl) * 64 + b] + redB[(3 * 4 + dl) * 64 + b]
                     + brol[dl];
            if (STAGE) stage[(t * DD + d0 + dl) * 64 + b] = xh;   // coalesced
            else       out[gbase + (size_t)t * DD] = xh;
            if (t < SS - 1) {
                float xi = (mv_pf > 0.5f) ? xv_pf : xh;
                ast4(&actg[(d0 + dl) * 64 + b], xi);
                ast4(&actg[(207 + d0 + dl) * 64 + b], mv_pf);
            }
        }
        if (t == SS - 1) break;

        // ---- arrive: xin published (payload drained before flag) ----
        ++gen;
        asm volatile("s_waitcnt vmcnt(0)" ::: "memory");
        __syncthreads();
        if (tid == 0)
            __hip_atomic_store(&flags[wg * 32], gen, __ATOMIC_RELAXED, AG);

        // ---- overlap poll window: gh partials (h_t already published) ----
        gemv12_pipe(actg, wgl, red, u, bp, 416 + wv * 64, hrow0 + wv * 64, 64, 4 + wv);

        // ---- wait: all xin flags ----
        if (tid < 64) {
            unsigned* f = &flags[tid * 32];
            while (__hip_atomic_load(f, __ATOMIC_RELAXED, AG) < gen) {}
        }
        __syncthreads();

        // ---- gate xin GEMV: 4 waves x 104 k (rows 414/415 zero-padded) ----
        gemv12_pipe(actg, wgl, red, u, bp, wv * 104, wv * 104, 104, wv);
        __syncthreads();

        // ---- combine + gates + publish h_{t+1} ----
        {
            const int u2 = tid >> 6, b2 = tid & 63;
            float gir = bihl[0 + u2], giz = bihl[4 + u2], gin = bihl[8 + u2];
            float ghr = bhhl[0 + u2], ghz = bhhl[4 + u2], ghn = bhhl[8 + u2];
            #pragma unroll
            for (int s = 0; s < 4; ++s) {
                gir += red[(s * 12 + 0 + u2) * 64 + b2];
                giz += red[(s * 12 + 4 + u2) * 64 + b2];
                gin += red[(s * 12 + 8 + u2) * 64 + b2];
                ghr += red[((4 + s) * 12 + 0 + u2) * 64 + b2];
                ghz += red[((4 + s) * 12 + 4 + u2) * 64 + b2];
                ghn += red[((4 + s) * 12 + 8 + u2) * 64 + b2];
            }
            float r = 1.f / (1.f + __expf(-(gir + ghr)));
            float z = 1.f / (1.f + __expf(-(giz + ghz)));
            float n = tanhf(gin + r * ghn);
            float hn = (1.f - z) * n + z * hloc[u2 * 64 + b2];
            hloc[u2 * 64 + b2] = hn;
            ast4(&actg[(HBASE + (par ^ 1) * 256 + wg * 4 + u2) * 64 + b2], hn);
        }

        // ---- arrive: h published ----
        ++gen;
        asm volatile("s_waitcnt vmcnt(0)" ::: "memory");
        __syncthreads();
        if (tid == 0)
            __hip_atomic_store(&flags[wg * 32], gen, __ATOMIC_RELAXED, AG);

        // ---- overlap poll window: next x/mask prefetch ----
        if (have && t + 1 < SS - 1) {
            xv_pf = x[gbase + (size_t)(t + 1) * DD];
            mv_pf = mask[gbase + (size_t)(t + 1) * DD];
        }

        // ---- wait: all h flags ----
        if (tid < 64) {
            unsigned* f = &flags[tid * 32];
            while (__hip_atomic_load(f, __ATOMIC_RELAXED, AG) < gen) {}
        }
        __syncthreads();
    }
}

// epilogue: stage[t][d][b] -> out[b][t][d], LDS transpose, fully coalesced
__global__ __launch_bounds__(256) void out_transpose(
    const float* __restrict__ stage, float* __restrict__ out)
{
    __shared__ float lds[DD * 65];
    const int t = blockIdx.x;
    const float* st = stage + (size_t)t * DD * 64;
    for (int i = threadIdx.x; i < DD * 64; i += 256) {
        int d = i >> 6, b = i & 63;
        lds[d * 65 + b] = st[i];
    }
    __syncthreads();
    for (int i = threadIdx.x; i < DD * 64; i += 256) {
        int b = i / DD, d = i - b * DD;
        out[(size_t)b * (SS * DD) + (size_t)t * DD + d] = lds[d * 65 + b];
    }
}

// ---- fallback (round-1 style, no workspace requirement) ----
__global__ __launch_bounds__(768) void rnn_fallback(
    const float* __restrict__ x, const float* __restrict__ mask,
    const float* __restrict__ W_ih, const float* __restrict__ W_hh,
    const float* __restrict__ b_ih, const float* __restrict__ b_hh,
    const float* __restrict__ W_ro, const float* __restrict__ b_ro,
    float* __restrict__ out)
{
    const int b = blockIdx.x, tid = threadIdx.x;
    __shared__ float h[HH];
    __shared__ float hnew[HH];
    __shared__ float xin[414 + 2];
    __shared__ float gi[768];
    __shared__ float gh[768];
    __shared__ float xhat[DD];
    const float bih = b_ih[tid], bhh = b_hh[tid];
    const float bro = (tid < DD) ? b_ro[tid] : 0.f;
    if (tid < HH) h[tid] = 0.f;
    if (tid < DD) xhat[tid] = bro;
    __syncthreads();
    const float* xb = x + (size_t)b * SS * DD;
    const float* mb = mask + (size_t)b * SS * DD;
    float* ob = out + (size_t)b * SS * DD;
    for (int t = 0; t < SS; ++t) {
        if (tid < DD) ob[t * DD + tid] = xhat[tid];
        if (t == SS - 1) break;
        if (tid < DD) {
            float m = mb[t * DD + tid], xv = xb[t * DD + tid];
            xin[tid] = (m > 0.5f) ? xv : xhat[tid];
            xin[DD + tid] = m;
        }
        __syncthreads();
        float accI = bih, accH = bhh;
        const float* wi = W_ih + (size_t)tid * 414;
        for (int k = 0; k < 414; ++k) accI += wi[k] * xin[k];
        const float* wh = W_hh + (size_t)tid * HH;
        for (int k = 0; k < HH; ++k) accH += wh[k] * h[k];
        gi[tid] = accI; gh[tid] = accH;
        __syncthreads();
        if (tid < HH) {
            float r = 1.f / (1.f + __expf(-(gi[tid] + gh[tid])));
            float z = 1.f / (1.f + __expf(-(gi[HH + tid] + gh[HH + tid])));
            float n = tanhf(gi[2 * HH + tid] + r * gh[2 * HH + tid]);
            hnew[tid] = (1.f - z) * n + z * h[tid];
        }
        __syncthreads();
        if (tid < DD) {
            float acc = bro;
            const float* wr = W_ro + (size_t)tid * HH;
            for (int k = 0; k < HH; ++k) acc += wr[k] * hnew[k];
            xhat[tid] = acc;
        }
        if (tid < HH) h[tid] = hnew[tid];
        __syncthreads();
    }
}

extern "C" void kernel_launch(void* const* d_in, const int* in_sizes, int n_in,
                              void* d_out, int out_size, void* d_ws, size_t ws_size,
                              hipStream_t stream) {
    const float* x    = (const float*)d_in[0];
    const float* mask = (const float*)d_in[1];
    const float* W_ih = (const float*)d_in[2];
    const float* W_hh = (const float*)d_in[3];
    const float* b_ih = (const float*)d_in[4];
    const float* b_hh = (const float*)d_in[5];
    const float* W_ro = (const float*)d_in[6];
    const float* b_ro = (const float*)d_in[7];
    float* out = (float*)d_out;
    float* ws  = (float*)d_ws;

    if (ws_size >= WS_FULL) {
        hipLaunchKernelGGL(rnn_init, dim3(32), dim3(256), 0, stream, ws);
        hipLaunchKernelGGL((rnn_persist<true>), dim3(NWG), dim3(256), 0, stream,
                           x, mask, W_ih, W_hh, b_ih, b_hh, W_ro, b_ro, ws, out);
        hipLaunchKernelGGL(out_transpose, dim3(SS), dim3(256), 0, stream,
                           ws + ACT_FLOATS + FLAG_FLOATS, out);
    } else if (ws_size >= WS_SMALL) {
        hipLaunchKernelGGL(rnn_init, dim3(32), dim3(256), 0, stream, ws);
        hipLaunchKernelGGL((rnn_persist<false>), dim3(NWG), dim3(256), 0, stream,
                           x, mask, W_ih, W_hh, b_ih, b_hh, W_ro, b_ro, ws, out);
    } else {
        hipLaunchKernelGGL(rnn_fallback, dim3(BB), dim3(768), 0, stream,
                           x, mask, W_ih, W_hh, b_ih, b_hh, W_ro, b_ro, out);
    }
}

// Round 6
// 6140.461 us; speedup vs baseline: 2.8695x; 2.8695x over previous
//
#include <hip/hip_runtime.h>
#include <math.h>

#define BB 64
#define SS 512
#define DD 207
#define HH 256
#define NWG 64
#define LDW 676   // wgl row stride (%32==4 -> staggered banks)
#define ROW 260   // wrol row stride
#define AG __HIP_MEMORY_SCOPE_AGENT

// ================= v6: step-slot rotation, fence-free =================
// 64 WGs x 256 threads. WG w owns hidden units [4w,4w+4) (12 gate rows) +
// readout rows [d0,d1). Weights LDS-resident. Each step t has its own slot:
//   rows 0..413  : xin_t (x-part 0..206, mask-part 207..413)
//   rows 414..415: pad (weights zero; poison harmless)
//   rows 416..671: h_t
// Writers: sc1 stores (write-through to L3). Readers: NORMAL cached loads of
// virgin addresses (flag-gated). Flags sc1, monotone.
#define SROWS 672
#define HOFF  416
#define SLOT  (SROWS * 64)
#define BUF_FLOATS ((size_t)SS * SLOT)
#define FLAG_U32 (64 * 32)
#define STAGE_FLOATS ((size_t)SS * DD * 64)
#define WS_NEED6 ((BUF_FLOATS + FLAG_U32 + STAGE_FLOATS) * sizeof(float))

// ---- v3 fallback layout (round-3 proven path) ----
#define V3_AROWS 928
#define V3_HBASE 416
#define V3_ACT (V3_AROWS * 64)
#define V3_FLAGS (64 * 32)
#define V3_WS_SMALL ((size_t)(V3_ACT + V3_FLAGS) * sizeof(float))
#define V3_WS_FULL  ((size_t)(V3_ACT + V3_FLAGS + STAGE_FLOATS) * sizeof(float))

__device__ __forceinline__ void ast4(float* p, float v) {
    union { float f; unsigned u; } c; c.f = v;
    __hip_atomic_store((unsigned*)p, c.u, __ATOMIC_RELAXED, AG);
}

// 12-row (3 gates x unit u) GEMV partial, NORMAL float4 loads (round-3 shape).
// gr0 = global float4-row base (t*672 + local row), wc0 = weight col base.
__device__ __forceinline__ void run_range6(
    const float4* __restrict__ A4, const float* __restrict__ wgl,
    float* __restrict__ red, int u, int bp, int wc0, int gr0, int len, int slot)
{
    float4 c0 = make_float4(0.f, 0.f, 0.f, 0.f);
    float4 c1 = c0, c2 = c0;
    #pragma unroll 4
    for (int k = 0; k < len; k += 4) {
        float4 a0 = A4[(gr0 + k + 0) * 16 + bp];
        float4 a1 = A4[(gr0 + k + 1) * 16 + bp];
        float4 a2 = A4[(gr0 + k + 2) * 16 + bp];
        float4 a3 = A4[(gr0 + k + 3) * 16 + bp];
        float4 w0 = *(const float4*)&wgl[(0 + u) * LDW + wc0 + k];
        float4 w1 = *(const float4*)&wgl[(4 + u) * LDW + wc0 + k];
        float4 w2 = *(const float4*)&wgl[(8 + u) * LDW + wc0 + k];
        c0.x += a0.x*w0.x + a1.x*w0.y + a2.x*w0.z + a3.x*w0.w;
        c0.y += a0.y*w0.x + a1.y*w0.y + a2.y*w0.z + a3.y*w0.w;
        c0.z += a0.z*w0.x + a1.z*w0.y + a2.z*w0.z + a3.z*w0.w;
        c0.w += a0.w*w0.x + a1.w*w0.y + a2.w*w0.z + a3.w*w0.w;
        c1.x += a0.x*w1.x + a1.x*w1.y + a2.x*w1.z + a3.x*w1.w;
        c1.y += a0.y*w1.x + a1.y*w1.y + a2.y*w1.z + a3.y*w1.w;
        c1.z += a0.z*w1.x + a1.z*w1.y + a2.z*w1.z + a3.z*w1.w;
        c1.w += a0.w*w1.x + a1.w*w1.y + a2.w*w1.z + a3.w*w1.w;
        c2.x += a0.x*w2.x + a1.x*w2.y + a2.x*w2.z + a3.x*w2.w;
        c2.y += a0.y*w2.x + a1.y*w2.y + a2.y*w2.z + a3.y*w2.w;
        c2.z += a0.z*w2.x + a1.z*w2.y + a2.z*w2.z + a3.z*w2.w;
        c2.w += a0.w*w2.x + a1.w*w2.y + a2.w*w2.z + a3.w*w2.w;
    }
    float4* R4 = (float4*)red;
    R4[(slot * 12 + 0 + u) * 16 + bp] = c0;
    R4[(slot * 12 + 4 + u) * 16 + bp] = c1;
    R4[(slot * 12 + 8 + u) * 16 + bp] = c2;
}

__global__ __launch_bounds__(256) void rnn_init6(float* __restrict__ ws) {
    int i = blockIdx.x * blockDim.x + threadIdx.x;
    // zero slot-0 h rows (h_0 = 0)
    for (int idx = i; idx < HH * 64; idx += gridDim.x * blockDim.x)
        ws[HOFF * 64 + idx] = 0.f;
    unsigned* fl = (unsigned*)(ws + BUF_FLOATS);
    for (int idx = i; idx < FLAG_U32; idx += gridDim.x * blockDim.x)
        fl[idx] = 0u;
}

__global__ __launch_bounds__(256) void rnn_persist6(
    const float* __restrict__ x, const float* __restrict__ mask,
    const float* __restrict__ W_ih, const float* __restrict__ W_hh,
    const float* __restrict__ b_ih, const float* __restrict__ b_hh,
    const float* __restrict__ W_ro, const float* __restrict__ b_ro,
    float* __restrict__ ws, float* __restrict__ out)
{
    const int wg = blockIdx.x;
    const int tid = threadIdx.x;
    const int lane = tid & 63;
    const int wv = tid >> 6;

    float* buf = ws;
    unsigned* flags = (unsigned*)(ws + BUF_FLOATS);
    float* stage = ws + BUF_FLOATS + FLAG_U32;

    __shared__ float wgl[12 * LDW];     // 12 gate rows x 676 (cols 414/415 = 0)
    __shared__ float wrol[4 * ROW];     // up to 4 readout rows
    __shared__ float red[8 * 12 * 64];  // slots 0-3 xin partials, 4-7 gh
    __shared__ float redB[16 * 64];     // readout partials
    __shared__ float hloc[4 * 64];      // own hidden units
    __shared__ float bihl[12], bhhl[12], brol[4];

    const int d0 = (207 * wg) / NWG;
    const int d1 = (207 * (wg + 1)) / NWG;
    const int dc = d1 - d0;

    for (int i = tid; i < 12 * LDW; i += 256) {
        int r = i / LDW, c = i - r * LDW;
        int rg = (r >> 2) * 256 + wg * 4 + (r & 3);
        float v = 0.f;
        if (c < 414) v = W_ih[rg * 414 + c];
        else if (c >= 416 && c < 672) v = W_hh[rg * 256 + (c - 416)];
        wgl[i] = v;
    }
    for (int i = tid; i < 4 * 256; i += 256) {
        int dl_ = i >> 8, j = i & 255;
        wrol[dl_ * ROW + j] = (dl_ < dc) ? W_ro[(d0 + dl_) * 256 + j] : 0.f;
    }
    if (tid < 12) {
        int rg = (tid >> 2) * 256 + wg * 4 + (tid & 3);
        bihl[tid] = b_ih[rg];
        bhhl[tid] = b_hh[rg];
    }
    if (tid < 4) brol[tid] = (tid < dc) ? b_ro[d0 + tid] : 0.f;
    hloc[tid] = 0.f;
    __syncthreads();

    const float4* A4 = (const float4*)buf;
    const int u  = lane >> 4;
    const int bp = lane & 15;

    const bool have = (tid < dc * 64);
    const int dl = tid >> 6, b = tid & 63;
    const size_t gbase = (size_t)b * (SS * DD) + (d0 + dl);
    float xv_pf = 0.f, mv_pf = 0.f;
    if (have) { xv_pf = x[gbase]; mv_pf = mask[gbase]; }

    unsigned gen = 0;

    for (int t = 0; t < SS; ++t) {
        const int sbase = t * SROWS;        // this step's slot (row units)

        // ---- Phase B: readout partials from h_t (virgin cached reads) ----
        {
            const float* hrow = buf + (size_t)(sbase + HOFF) * 64;
            const int jb = wv * 64;
            float acc0 = 0.f, acc1 = 0.f, acc2 = 0.f, acc3 = 0.f;
            #pragma unroll 4
            for (int j = 0; j < 64; j += 4) {
                float a0 = hrow[(jb + j + 0) * 64 + lane];
                float a1 = hrow[(jb + j + 1) * 64 + lane];
                float a2 = hrow[(jb + j + 2) * 64 + lane];
                float a3 = hrow[(jb + j + 3) * 64 + lane];
                float4 w0 = *(const float4*)&wrol[0 * ROW + jb + j];
                float4 w1 = *(const float4*)&wrol[1 * ROW + jb + j];
                float4 w2 = *(const float4*)&wrol[2 * ROW + jb + j];
                float4 w3 = *(const float4*)&wrol[3 * ROW + jb + j];
                acc0 += a0*w0.x + a1*w0.y + a2*w0.z + a3*w0.w;
                acc1 += a0*w1.x + a1*w1.y + a2*w1.z + a3*w1.w;
                acc2 += a0*w2.x + a1*w2.y + a2*w2.z + a3*w2.w;
                acc3 += a0*w3.x + a1*w3.y + a2*w3.z + a3*w3.w;
            }
            redB[(wv * 4 + 0) * 64 + lane] = acc0;
            redB[(wv * 4 + 1) * 64 + lane] = acc1;
            redB[(wv * 4 + 2) * 64 + lane] = acc2;
            redB[(wv * 4 + 3) * 64 + lane] = acc3;
        }
        __syncthreads();
        if (have) {
            float xh = redB[(0 * 4 + dl) * 64 + b] + redB[(1 * 4 + dl) * 64 + b]
                     + redB[(2 * 4 + dl) * 64 + b] + redB[(3 * 4 + dl) * 64 + b]
                     + brol[dl];
            stage[(t * DD + d0 + dl) * 64 + b] = xh;   // coalesced, normal
            if (t < SS - 1) {
                float xi = (mv_pf > 0.5f) ? xv_pf : xh;
                ast4(&buf[(size_t)(sbase + d0 + dl) * 64 + b], xi);        // sc1
                ast4(&buf[(size_t)(sbase + 207 + d0 + dl) * 64 + b], mv_pf);
            }
        }
        if (t == SS - 1) break;

        // ---- arrive 1: xin_t published ----
        ++gen;
        asm volatile("s_waitcnt vmcnt(0)" ::: "memory");
        __syncthreads();
        if (tid == 0)
            __hip_atomic_store(&flags[wg * 32], gen, __ATOMIC_RELAXED, AG);

        // ---- overlap: gh partials from h_t (L1/L2-hot: same rows as Phase B) ----
        run_range6(A4, wgl, red, u, bp, 416 + wv * 64, sbase + HOFF + wv * 64, 64, 4 + wv);

        // ---- wait 1 ----
        if (tid < 64) {
            unsigned* f = &flags[tid * 32];
            while (__hip_atomic_load(f, __ATOMIC_RELAXED, AG) < gen) {}
        }
        __syncthreads();

        // ---- gate xin GEMV: 4 waves x 104 rows (virgin cached reads) ----
        run_range6(A4, wgl, red, u, bp, wv * 104, sbase + wv * 104, 104, wv);
        __syncthreads();

        // ---- combine + gates + publish h_{t+1} into slot t+1 (sc1) ----
        {
            const int u2 = tid >> 6, b2 = tid & 63;
            float gir = bihl[0 + u2], giz = bihl[4 + u2], gin = bihl[8 + u2];
            float ghr = bhhl[0 + u2], ghz = bhhl[4 + u2], ghn = bhhl[8 + u2];
            #pragma unroll
            for (int s = 0; s < 4; ++s) {
                gir += red[(s * 12 + 0 + u2) * 64 + b2];
                giz += red[(s * 12 + 4 + u2) * 64 + b2];
                gin += red[(s * 12 + 8 + u2) * 64 + b2];
                ghr += red[((4 + s) * 12 + 0 + u2) * 64 + b2];
                ghz += red[((4 + s) * 12 + 4 + u2) * 64 + b2];
                ghn += red[((4 + s) * 12 + 8 + u2) * 64 + b2];
            }
            float r = 1.f / (1.f + __expf(-(gir + ghr)));
            float z = 1.f / (1.f + __expf(-(giz + ghz)));
            float n = tanhf(gin + r * ghn);
            float hn = (1.f - z) * n + z * hloc[u2 * 64 + b2];
            hloc[u2 * 64 + b2] = hn;
            ast4(&buf[(size_t)((t + 1) * SROWS + HOFF + wg * 4 + u2) * 64 + b2], hn);
        }

        // ---- arrive 2: h_{t+1} published ----
        ++gen;
        asm volatile("s_waitcnt vmcnt(0)" ::: "memory");
        __syncthreads();
        if (tid == 0)
            __hip_atomic_store(&flags[wg * 32], gen, __ATOMIC_RELAXED, AG);

        // ---- overlap: next x/mask prefetch ----
        if (have && t + 1 < SS - 1) {
            xv_pf = x[gbase + (size_t)(t + 1) * DD];
            mv_pf = mask[gbase + (size_t)(t + 1) * DD];
        }

        // ---- wait 2 ----
        if (tid < 64) {
            unsigned* f = &flags[tid * 32];
            while (__hip_atomic_load(f, __ATOMIC_RELAXED, AG) < gen) {}
        }
        __syncthreads();
    }
}

// epilogue: stage[t][d][b] -> out[b][t][d]
__global__ __launch_bounds__(256) void out_transpose(
    const float* __restrict__ stage, float* __restrict__ out)
{
    __shared__ float lds[DD * 65];
    const int t = blockIdx.x;
    const float* st = stage + (size_t)t * DD * 64;
    for (int i = threadIdx.x; i < DD * 64; i += 256) {
        int d = i >> 6, b = i & 63;
        lds[d * 65 + b] = st[i];
    }
    __syncthreads();
    for (int i = threadIdx.x; i < DD * 64; i += 256) {
        int b = i / DD, d = i - b * DD;
        out[(size_t)b * (SS * DD) + (size_t)t * DD + d] = lds[d * 65 + b];
    }
}

// ================= v3 middle fallback (round-3 proven, 8.1 ms) =================
__device__ __forceinline__ void v3_gbar(unsigned* flags, int wg, unsigned g) {
    __syncthreads();
    if (threadIdx.x < 64) {
        if (threadIdx.x == 0) {
            __builtin_amdgcn_fence(__ATOMIC_RELEASE, "agent");
            __hip_atomic_store(&flags[wg * 32], g, __ATOMIC_RELAXED, AG);
        }
        unsigned* f = &flags[threadIdx.x * 32];
        while (__hip_atomic_load(f, __ATOMIC_RELAXED, AG) < g) { }
        __builtin_amdgcn_fence(__ATOMIC_ACQUIRE, "agent");
    }
    __syncthreads();
}

__global__ __launch_bounds__(256) void v3_init(float* __restrict__ ws) {
    int i = blockIdx.x * blockDim.x + threadIdx.x;
    const int nz = (672 - 414) * 64;
    for (int idx = i; idx < nz; idx += gridDim.x * blockDim.x)
        ws[414 * 64 + idx] = 0.f;
    for (int idx = i; idx < V3_FLAGS; idx += gridDim.x * blockDim.x)
        ((unsigned*)(ws + V3_ACT))[idx] = 0u;
}

template<bool STAGE>
__global__ __launch_bounds__(256) void v3_persist(
    const float* __restrict__ x, const float* __restrict__ mask,
    const float* __restrict__ W_ih, const float* __restrict__ W_hh,
    const float* __restrict__ b_ih, const float* __restrict__ b_hh,
    const float* __restrict__ W_ro, const float* __restrict__ b_ro,
    float* __restrict__ ws, float* __restrict__ out)
{
    const int wg = blockIdx.x;
    const int tid = threadIdx.x;
    const int lane = tid & 63;
    const int wv = tid >> 6;

    float* actg = ws;
    unsigned* flags = (unsigned*)(ws + V3_ACT);
    float* stage = ws + V3_ACT + V3_FLAGS;

    __shared__ float wgl[12 * LDW];
    __shared__ float wrol[4 * 256];
    __shared__ float red[5 * 12 * 64];
    __shared__ float redB[16 * 64];
    __shared__ float hloc[4 * 64];
    __shared__ float bihl[12], bhhl[12], brol[4];

    const int d0 = (207 * wg) / NWG;
    const int d1 = (207 * (wg + 1)) / NWG;
    const int dc = d1 - d0;

    for (int i = tid; i < 12 * LDW; i += 256) {
        int r = i / LDW, c = i - r * LDW;
        int rg = (r >> 2) * 256 + wg * 4 + (r & 3);
        float v = 0.f;
        if (c < 414) v = W_ih[rg * 414 + c];
        else if (c >= 416 && c < 672) v = W_hh[rg * 256 + (c - 416)];
        wgl[i] = v;
    }
    for (int i = tid; i < 4 * 256; i += 256) {
        int dl_ = i >> 8, j = i & 255;
        wrol[i] = (dl_ < dc) ? W_ro[(d0 + dl_) * 256 + j] : 0.f;
    }
    if (tid < 12) {
        int rg = (tid >> 2) * 256 + wg * 4 + (tid & 3);
        bihl[tid] = b_ih[rg];
        bhhl[tid] = b_hh[rg];
    }
    if (tid < 4) brol[tid] = (tid < dc) ? b_ro[d0 + tid] : 0.f;
    hloc[tid] = 0.f;
    __syncthreads();

    const float4* A4 = (const float4*)actg;
    const int u = lane >> 4;
    const int bp = lane & 15;

    const bool have = (tid < dc * 64);
    const int dl = tid >> 6, b = tid & 63;
    const size_t gbase = (size_t)b * (SS * DD) + (d0 + dl);
    float xv_pf = 0.f, mv_pf = 0.f;
    if (have) { xv_pf = x[gbase]; mv_pf = mask[gbase]; }

    unsigned gen = 0;

    for (int t = 0; t < SS; ++t) {
        const int par = t & 1;
        const int hrow0 = V3_HBASE + par * 256;

        {
            const float* hrow = actg + hrow0 * 64;
            const int jb = wv * 64;
            float acc0 = 0.f, acc1 = 0.f, acc2 = 0.f, acc3 = 0.f;
            #pragma unroll 4
            for (int j = 0; j < 64; j += 4) {
                float a0 = hrow[(jb + j + 0) * 64 + lane];
                float a1 = hrow[(jb + j + 1) * 64 + lane];
                float a2 = hrow[(jb + j + 2) * 64 + lane];
                float a3 = hrow[(jb + j + 3) * 64 + lane];
                float4 w0 = *(const float4*)&wrol[0 * 256 + jb + j];
                float4 w1 = *(const float4*)&wrol[1 * 256 + jb + j];
                float4 w2 = *(const float4*)&wrol[2 * 256 + jb + j];
                float4 w3 = *(const float4*)&wrol[3 * 256 + jb + j];
                acc0 += a0*w0.x + a1*w0.y + a2*w0.z + a3*w0.w;
                acc1 += a0*w1.x + a1*w1.y + a2*w1.z + a3*w1.w;
                acc2 += a0*w2.x + a1*w2.y + a2*w2.z + a3*w2.w;
                acc3 += a0*w3.x + a1*w3.y + a2*w3.z + a3*w3.w;
            }
            redB[(wv * 4 + 0) * 64 + lane] = acc0;
            redB[(wv * 4 + 1) * 64 + lane] = acc1;
            redB[(wv * 4 + 2) * 64 + lane] = acc2;
            redB[(wv * 4 + 3) * 64 + lane] = acc3;
        }
        __syncthreads();
        if (have) {
            float xh = redB[(0 * 4 + dl) * 64 + b] + redB[(1 * 4 + dl) * 64 + b]
                     + redB[(2 * 4 + dl) * 64 + b] + redB[(3 * 4 + dl) * 64 + b]
                     + brol[dl];
            if (STAGE) stage[(t * DD + d0 + dl) * 64 + b] = xh;
            else       out[gbase + (size_t)t * DD] = xh;
            if (t < SS - 1) {
                float xi = (mv_pf > 0.5f) ? xv_pf : xh;
                actg[(d0 + dl) * 64 + b] = xi;
                actg[(207 + d0 + dl) * 64 + b] = mv_pf;
            }
        }
        if (t == SS - 1) break;

        if (have && t + 1 < SS - 1) {
            xv_pf = x[gbase + (size_t)(t + 1) * DD];
            mv_pf = mask[gbase + (size_t)(t + 1) * DD];
        }

        v3_gbar(flags, wg, ++gen);

        // gates: 4-wave k-split over xin(416) + h(256), round-3 split
        if (wv == 0)      run_range6(A4, wgl, red, u, bp, 0,   0,          168, 0);
        else if (wv == 1) run_range6(A4, wgl, red, u, bp, 168, 168,        168, 1);
        else if (wv == 2) {
            run_range6(A4, wgl, red, u, bp, 336, 336,        80,  2);
            run_range6(A4, wgl, red, u, bp, 416, hrow0,      96,  3);
        } else            run_range6(A4, wgl, red, u, bp, 512, hrow0 + 96, 160, 4);
        __syncthreads();
        {
            const int u2 = tid >> 6, b2 = tid & 63;
            float gir = red[(0*12 + 0 + u2)*64 + b2] + red[(1*12 + 0 + u2)*64 + b2]
                      + red[(2*12 + 0 + u2)*64 + b2] + bihl[0 + u2];
            float giz = red[(0*12 + 4 + u2)*64 + b2] + red[(1*12 + 4 + u2)*64 + b2]
                      + red[(2*12 + 4 + u2)*64 + b2] + bihl[4 + u2];
            float gin = red[(0*12 + 8 + u2)*64 + b2] + red[(1*12 + 8 + u2)*64 + b2]
                      + red[(2*12 + 8 + u2)*64 + b2] + bihl[8 + u2];
            float ghr = red[(3*12 + 0 + u2)*64 + b2] + red[(4*12 + 0 + u2)*64 + b2] + bhhl[0 + u2];
            float ghz = red[(3*12 + 4 + u2)*64 + b2] + red[(4*12 + 4 + u2)*64 + b2] + bhhl[4 + u2];
            float ghn = red[(3*12 + 8 + u2)*64 + b2] + red[(4*12 + 8 + u2)*64 + b2] + bhhl[8 + u2];
            float r = 1.f / (1.f + __expf(-(gir + ghr)));
            float z = 1.f / (1.f + __expf(-(giz + ghz)));
            float n = tanhf(gin + r * ghn);
            float hn = (1.f - z) * n + z * hloc[u2 * 64 + b2];
            hloc[u2 * 64 + b2] = hn;
            actg[(V3_HBASE + (par ^ 1) * 256 + wg * 4 + u2) * 64 + b2] = hn;
        }
        v3_gbar(flags, wg, ++gen);
    }
}

// ---- minimal fallback (one WG per batch) ----
__global__ __launch_bounds__(768) void rnn_fallback(
    const float* __restrict__ x, const float* __restrict__ mask,
    const float* __restrict__ W_ih, const float* __restrict__ W_hh,
    const float* __restrict__ b_ih, const float* __restrict__ b_hh,
    const float* __restrict__ W_ro, const float* __restrict__ b_ro,
    float* __restrict__ out)
{
    const int b = blockIdx.x, tid = threadIdx.x;
    __shared__ float h[HH];
    __shared__ float hnew[HH];
    __shared__ float xin[414 + 2];
    __shared__ float gi[768];
    __shared__ float gh[768];
    __shared__ float xhat[DD];
    const float bih = b_ih[tid], bhh = b_hh[tid];
    const float bro = (tid < DD) ? b_ro[tid] : 0.f;
    if (tid < HH) h[tid] = 0.f;
    if (tid < DD) xhat[tid] = bro;
    __syncthreads();
    const float* xb = x + (size_t)b * SS * DD;
    const float* mb = mask + (size_t)b * SS * DD;
    float* ob = out + (size_t)b * SS * DD;
    for (int t = 0; t < SS; ++t) {
        if (tid < DD) ob[t * DD + tid] = xhat[tid];
        if (t == SS - 1) break;
        if (tid < DD) {
            float m = mb[t * DD + tid], xv = xb[t * DD + tid];
            xin[tid] = (m > 0.5f) ? xv : xhat[tid];
            xin[DD + tid] = m;
        }
        __syncthreads();
        float accI = bih, accH = bhh;
        const float* wi = W_ih + (size_t)tid * 414;
        for (int k = 0; k < 414; ++k) accI += wi[k] * xin[k];
        const float* wh = W_hh + (size_t)tid * HH;
        for (int k = 0; k < HH; ++k) accH += wh[k] * h[k];
        gi[tid] = accI; gh[tid] = accH;
        __syncthreads();
        if (tid < HH) {
            float r = 1.f / (1.f + __expf(-(gi[tid] + gh[tid])));
            float z = 1.f / (1.f + __expf(-(gi[HH + tid] + gh[HH + tid])));
            float n = tanhf(gi[2 * HH + tid] + r * gh[2 * HH + tid]);
            hnew[tid] = (1.f - z) * n + z * h[tid];
        }
        __syncthreads();
        if (tid < DD) {
            float acc = bro;
            const float* wr = W_ro + (size_t)tid * HH;
            for (int k = 0; k < HH; ++k) acc += wr[k] * hnew[k];
            xhat[tid] = acc;
        }
        if (tid < HH) h[tid] = hnew[tid];
        __syncthreads();
    }
}

extern "C" void kernel_launch(void* const* d_in, const int* in_sizes, int n_in,
                              void* d_out, int out_size, void* d_ws, size_t ws_size,
                              hipStream_t stream) {
    const float* x    = (const float*)d_in[0];
    const float* mask = (const float*)d_in[1];
    const float* W_ih = (const float*)d_in[2];
    const float* W_hh = (const float*)d_in[3];
    const float* b_ih = (const float*)d_in[4];
    const float* b_hh = (const float*)d_in[5];
    const float* W_ro = (const float*)d_in[6];
    const float* b_ro = (const float*)d_in[7];
    float* out = (float*)d_out;
    float* ws  = (float*)d_ws;

    if (ws_size >= WS_NEED6) {
        hipLaunchKernelGGL(rnn_init6, dim3(64), dim3(256), 0, stream, ws);
        hipLaunchKernelGGL(rnn_persist6, dim3(NWG), dim3(256), 0, stream,
                           x, mask, W_ih, W_hh, b_ih, b_hh, W_ro, b_ro, ws, out);
        hipLaunchKernelGGL(out_transpose, dim3(SS), dim3(256), 0, stream,
                           ws + BUF_FLOATS + FLAG_U32, out);
    } else if (ws_size >= V3_WS_FULL) {
        hipLaunchKernelGGL(v3_init, dim3(32), dim3(256), 0, stream, ws);
        hipLaunchKernelGGL((v3_persist<true>), dim3(NWG), dim3(256), 0, stream,
                           x, mask, W_ih, W_hh, b_ih, b_hh, W_ro, b_ro, ws, out);
        hipLaunchKernelGGL(out_transpose, dim3(SS), dim3(256), 0, stream,
                           ws + V3_ACT + V3_FLAGS, out);
    } else if (ws_size >= V3_WS_SMALL) {
        hipLaunchKernelGGL(v3_init, dim3(32), dim3(256), 0, stream, ws);
        hipLaunchKernelGGL((v3_persist<false>), dim3(NWG), dim3(256), 0, stream,
                           x, mask, W_ih, W_hh, b_ih, b_hh, W_ro, b_ro, ws, out);
    } else {
        hipLaunchKernelGGL(rnn_fallback, dim3(BB), dim3(768), 0, stream,
                           x, mask, W_ih, W_hh, b_ih, b_hh, W_ro, b_ro, out);
    }
}